// Round 4
// baseline (212.426 us; speedup 1.0000x reference)
//
#include <hip/hip_runtime.h>
#include <math.h>

#define NA 360
#define NP 512
#define NB 16
#define IMG 512
#define ACH 8                // angles per LDS chunk
#define NCH (NA / ACH)       // 45 chunks
#define NPT 32               // LDS points per angle (span <= 25 incl. margins)
#define PS 514               // p' in [0,513]
#define PS_GUARD (PS - NPT)  // 482

typedef unsigned int uint32;
typedef __fp16 half2 __attribute__((ext_vector_type(2)));   // builtin V2h type

static __device__ __forceinline__ half2 u2h(uint32 u) {
    union { uint32 u; half2 h; } v; v.u = u; return v.h;
}
static __device__ __forceinline__ uint32 pk(float a, float b) {
    union { half2 h; uint32 u; } v;
    v.h = __builtin_amdgcn_cvt_pkrtz(a, b);
    return v.u;
}

#if __has_builtin(__builtin_amdgcn_fdot2)
static __device__ __forceinline__ float dot2(half2 w, half2 v, float acc) {
    return __builtin_amdgcn_fdot2(w, v, acc, false);
}
#else
static __device__ __forceinline__ float dot2(half2 w, half2 v, float acc) {
    return fmaf((float)w.x, (float)v.x, fmaf((float)w.y, (float)v.y, acc));
}
#endif

// tab[a] = {c'=cos/dp, s'=sin/dp, off=-pos0/dp, (|c'|+|s'|)*7.5 (block half-span)}
static __device__ __forceinline__ void write_tab(const float* thetas,
                                                 const float* positions,
                                                 float4* tab, int a) {
    double th = (double)thetas[a];
    double p0 = (double)positions[0];
    double dp = (double)positions[1] - p0;
    double c = cos(th) / dp, s = sin(th) / dp;
    tab[a] = make_float4((float)c, (float)s, (float)(-p0 / dp),
                         (float)((fabs(c) + fabs(s)) * 7.5));
}

// Window start with 1-point lower margin against fp rounding (round-8 lesson).
static __device__ __forceinline__ int pmin_of(float tc, float tw) {
    float fmn = fminf(fmaxf(tc - tw, -1.0f), 512.0f);
    return min(max((int)floorf(fmn) - 1, 0), PS_GUARD);
}

// Tiny kernel: tab only (360 fp64 trig). ~2 us. Keeps the big kernel's inner
// loop on the zero-VALU s_load tab path (tab written by a DIFFERENT kernel ->
// scalar-cache safe; same-kernel tab writes would risk stale K$ reads).
__global__ void tabk(const float* __restrict__ thetas,
                     const float* __restrict__ positions,
                     float4* __restrict__ tab) {
    int a = blockIdx.x * 64 + threadIdx.x;
    if (a < NA) write_tab(thetas, positions, tab, a);
}

// ---------------------------------------------------------------------------
// Round-16 (= round-15 with the PS_GUARD macro-ordering compile fix):
// SELF-STAGING backproject — no st array, no stage kernel, no grid barrier.
// Rounds 13/14 proved in-kernel grid barriers cost ~80 us regardless of
// implementation (CG 194.0 us == salt-flag 194.5 us) — structural, dead end.
// Instead each block stages its own chunk windows straight from sino: per
// (angle, plane, point) slot, load the two f32 taps (one unsigned-compare
// mask each for detector edges), v_cvt_pkrtz-pack, ds_write_b128 into the
// SAME double-buffered LDS layout the proven round-10 inner loop reads.
// Inner loop is UNCHANGED (113.5 us = 98% of the ds_read_b128 issue roofline,
// conflicts 0; hybrid TA/LDS splits regressed twice — do not revisit).
// Staging adds ~100 VALU + 32 VMEM per thread-chunk (VALUBusy ~68->90%),
// which must stay under the LDS pipe to keep LDS critical: __launch_bounds__
// (256,4) pins VGPR<=128 so 4 blocks/CU (16 waves) is preserved.
// Removes: 740k-thread stage kernel, 11.8 MB st write + ~63 MB st refetch.
// ---------------------------------------------------------------------------
__launch_bounds__(256, 4)
__global__ void backproject(const float* __restrict__ sino,
                            const float4* __restrict__ tab,
                            float* __restrict__ out) {
    __shared__ uint4 buf[2][ACH * 4 * NPT];     // 2 x 16 KB, [al][q][pt]
    __shared__ int pm_lds[NA];                  // 1.44 KB
    const int tid = threadIdx.y * 16 + threadIdx.x;
    const int x = blockIdx.x * 16 + threadIdx.x;
    const int y = blockIdx.y * 16 + threadIdx.y;
    const float xs = (float)x - 255.5f;
    const float ys = (float)y - 255.5f;
    const float xc = (float)(blockIdx.x * 16) + 7.5f - 255.5f;   // block center
    const float yc = (float)(blockIdx.y * 16) + 7.5f - 255.5f;

    // ---- prologue: block-uniform pmin for every angle ----
    for (int a = tid; a < NA; a += 256) {
        const float4 t = tab[a];
        float tc = fmaf(xc, t.x, fmaf(yc, t.y, t.z));
        pm_lds[a] = pmin_of(tc, t.w);
    }
    __syncthreads();

    float acc[NB];
#pragma unroll
    for (int b = 0; b < NB; ++b) acc[b] = 0.0f;

    const int qld = (tid >> 5) & 3;             // this thread's staging plane
    const int ptl = tid & 31;                   // this thread's staging point
    const int hl  = tid >> 7;                   // odd/even angle (wave-uniform)
    const int hls = __builtin_amdgcn_readfirstlane(hl);

    // Per-thread row-plane base pointers (batches 4*qld .. 4*qld+3).
    const float* plane[4];
#pragma unroll
    for (int i = 0; i < 4; ++i)
        plane[i] = sino + (size_t)(4 * qld + i) * (NA * NP);

    // Stage chunk ch's windows into buf[bsel]: slot j covers angle 2j+hls.
    // Tap pair at point pp: (s[pp-1], s[pp]); valid masks are single unsigned
    // compares: f0 valid iff (pp-1) u< 512, f1 valid iff pp u< 512.
    auto stage = [&](int ch, int bsel) {
#pragma unroll
        for (int j = 0; j < 4; ++j) {
            const int a  = ch * ACH + 2 * j + hls;
            const int pm = pm_lds[a];
            const int pp = pm + ptl;                     // [0, 513]
            const int o0 = min(max(pp - 1, 0), NP - 1);
            const int o1 = min(pp, NP - 1);
            const bool v0 = (uint32)(pp - 1) < (uint32)NP;
            const bool v1 = (uint32)pp < (uint32)NP;
            const size_t ro = (size_t)a * NP;
            uint32 r[4];
#pragma unroll
            for (int i = 0; i < 4; ++i) {
                float f0 = plane[i][ro + o0];
                float f1 = plane[i][ro + o1];
                f0 = v0 ? f0 : 0.0f;
                f1 = v1 ? f1 : 0.0f;
                r[i] = pk(f0, f1);
            }
            buf[bsel][tid + 256 * j] = make_uint4(r[0], r[1], r[2], r[3]);
        }
    };

    stage(0, 0);
    __syncthreads();                            // buf[0] ready

#pragma unroll 1
    for (int ch = 0; ch < NCH; ++ch) {
        // Stage next chunk into the buffer freed by the previous barrier;
        // loads' latency hides under this wave's compute + other waves (TLP).
        if (ch + 1 < NCH) stage(ch + 1, (ch + 1) & 1);

        const int a0 = ch * ACH;
        const uint4* b = buf[ch & 1];
#pragma unroll
        for (int al = 0; al < ACH; ++al) {
            const float4 t = tab[a0 + al];      // uniform -> s_load (free)
            float fidx = fmaf(xs, t.x, fmaf(ys, t.y, t.z));
            fidx = fminf(fmaxf(fidx, -1.0f), 512.0f);
            const float fl = floorf(fidx);
            const float w = fidx - fl;
            const half2 wp = u2h(pk(1.0f - w, w));
            const int idx = ((int)fl + 1) - pm_lds[a0 + al];   // [0, 31]
            const uint4 d0 = b[al * 128 + 0 * 32 + idx];
            const uint4 d1 = b[al * 128 + 1 * 32 + idx];
            const uint4 d2 = b[al * 128 + 2 * 32 + idx];
            const uint4 d3 = b[al * 128 + 3 * 32 + idx];
            acc[0]  = dot2(wp, u2h(d0.x), acc[0]);
            acc[1]  = dot2(wp, u2h(d0.y), acc[1]);
            acc[2]  = dot2(wp, u2h(d0.z), acc[2]);
            acc[3]  = dot2(wp, u2h(d0.w), acc[3]);
            acc[4]  = dot2(wp, u2h(d1.x), acc[4]);
            acc[5]  = dot2(wp, u2h(d1.y), acc[5]);
            acc[6]  = dot2(wp, u2h(d1.z), acc[6]);
            acc[7]  = dot2(wp, u2h(d1.w), acc[7]);
            acc[8]  = dot2(wp, u2h(d2.x), acc[8]);
            acc[9]  = dot2(wp, u2h(d2.y), acc[9]);
            acc[10] = dot2(wp, u2h(d2.z), acc[10]);
            acc[11] = dot2(wp, u2h(d2.w), acc[11]);
            acc[12] = dot2(wp, u2h(d3.x), acc[12]);
            acc[13] = dot2(wp, u2h(d3.y), acc[13]);
            acc[14] = dot2(wp, u2h(d3.z), acc[14]);
            acc[15] = dot2(wp, u2h(d3.w), acc[15]);
        }
        __syncthreads();                        // all reads of buf[ch&1] done;
                                                // all writes of buf[(ch+1)&1] done
    }

    const size_t pix = (size_t)y * IMG + x;
#pragma unroll
    for (int b = 0; b < NB; ++b)
        out[(size_t)b * (IMG * IMG) + pix] = acc[b];
}

extern "C" void kernel_launch(void* const* d_in, const int* in_sizes, int n_in,
                              void* d_out, int out_size, void* d_ws, size_t ws_size,
                              hipStream_t stream) {
    const float* sino      = (const float*)d_in[0];
    const float* thetas    = (const float*)d_in[1];
    const float* positions = (const float*)d_in[2];
    float* out = (float*)d_out;

    float4* tab = (float4*)d_ws;                     // 360 * 16 B

    tabk<<<dim3((NA + 63) / 64), dim3(64), 0, stream>>>(thetas, positions, tab);
    backproject<<<dim3(IMG / 16, IMG / 16), dim3(16, 16), 0, stream>>>(sino, tab, out);
}

// Round 5
// 175.109 us; speedup vs baseline: 1.2131x; 1.2131x over previous
//
#include <hip/hip_runtime.h>
#include <math.h>

#define NA 360
#define NP 512
#define NB 16
#define IMG 512
#define ACH 8                // angles per LDS chunk
#define NCH (NA / ACH)       // 45 chunks
#define NPT 32               // LDS points per angle (span <= 25 incl. margins)
#define PS 514               // p' in [0,513]; entry p' holds taps (s[p'-1], s[p'])
#define PS_GUARD (PS - NPT)  // 482

typedef unsigned int uint32;
typedef __fp16 half2 __attribute__((ext_vector_type(2)));   // builtin V2h type

static __device__ __forceinline__ half2 u2h(uint32 u) {
    union { uint32 u; half2 h; } v; v.u = u; return v.h;
}
static __device__ __forceinline__ uint32 pk(float a, float b) {
    union { half2 h; uint32 u; } v;
    v.h = __builtin_amdgcn_cvt_pkrtz(a, b);
    return v.u;
}

#if __has_builtin(__builtin_amdgcn_fdot2)
static __device__ __forceinline__ float dot2(half2 w, half2 v, float acc) {
    return __builtin_amdgcn_fdot2(w, v, acc, false);
}
#else
static __device__ __forceinline__ float dot2(half2 w, half2 v, float acc) {
    return fmaf((float)w.x, (float)v.x, fmaf((float)w.y, (float)v.y, acc));
}
#endif

// tab[a] = {c'=cos/dp, s'=sin/dp, off=-pos0/dp, (|c'|+|s'|)*7.5 (block half-span)}
static __device__ __forceinline__ void write_tab(const float* thetas,
                                                 const float* positions,
                                                 float4* tab, int a) {
    double th = (double)thetas[a];
    double p0 = (double)positions[0];
    double dp = (double)positions[1] - p0;
    double c = cos(th) / dp, s = sin(th) / dp;
    tab[a] = make_float4((float)c, (float)s, (float)(-p0 / dp),
                         (float)((fabs(c) + fabs(s)) * 7.5));
}

// Window start with 1-point lower margin against fp rounding (round-8 lesson).
static __device__ __forceinline__ int pmin_of(float tc, float tw) {
    float fmn = fminf(fmaxf(tc - tw, -1.0f), 512.0f);
    return min(max((int)floorf(fmn) - 1, 0), PS_GUARD);
}

// ---------------------------------------------------------------------------
// Round-17 VECTORIZED stage. Round-4 lesson: in-kernel scalar-gather staging
// costs ~22+ VALU/entry (self-staging added +45 us VALU-busy) — the same math
// made the OLD stage kernel ~14 us. This version cuts per-entry cost ~4x:
// one thread stages 8 consecutive entries of one (plane, angle) row.
//   - entries pp = 8g+1..8g+8 need taps s[8g..8g+8]: two aligned dwordx4
//     loads + the 9th value via __shfl_down from the neighbor lane (lane g+1
//     holds s[8(g+1)] in lo.x) — zero extra loads, zero edge masks except
//     lane 63 (s[512] OOB -> 0, matching f1-validity: pp=512 -> (s[511],0)).
//   - f0 = s[pp-1] is ALWAYS valid for pp in [1,512] (pp-1 in [0,511]).
//   - 8 contiguous uint4 stores per thread (wave writes 8 KB contiguous).
// Block = one angle (4 planes x 64 groups = 256 thr); block 360 does the two
// edge entries per (k,a) row (pp=0 -> (0,s[0]); pp=513 -> zeros) + tab.
// Backproject is the proven round-10 kernel VERBATIM (113.5 us = 98% of the
// ds_read_b128 issue roofline, conflicts 0; 4xb128 per pixel-angle is
// layout-minimal). Grid-barrier fusion (r13/14: +80 us) and self-staging
// (r16: +58 us) both disproven — two-kernel structure is final.
// Budget: ~40 us fixed harness overhead + 113.7 backproject + ~7 stage.
// ---------------------------------------------------------------------------
__launch_bounds__(256)
__global__ void stage(const float* __restrict__ sino,
                      const float* __restrict__ thetas,
                      const float* __restrict__ positions,
                      float4* __restrict__ tab,
                      uint4* __restrict__ st) {
    const int tid = threadIdx.x;
    if (blockIdx.x == NA) {                       // edges + tab block
        for (int a = tid; a < NA; a += 256)
            write_tab(thetas, positions, tab, a);
        for (int n = tid; n < 4 * NA; n += 256) {
            const int k = n / NA;
            const int a = n - k * NA;
            const size_t base = ((size_t)k * NA + a) * PS;
            uint32 r[4];
#pragma unroll
            for (int i = 0; i < 4; ++i)
                r[i] = pk(0.0f, sino[((size_t)(4 * k + i) * NA + a) * NP]);
            st[base] = make_uint4(r[0], r[1], r[2], r[3]);
            st[base + (PS - 1)] = make_uint4(0u, 0u, 0u, 0u);
        }
        return;
    }

    const int a = blockIdx.x;                     // angle
    const int k = tid >> 6;                       // plane (== wave id)
    const int g = tid & 63;                       // group: pp = 8g+1 .. 8g+8

    uint32 e[4][8];
#pragma unroll
    for (int i = 0; i < 4; ++i) {                 // batch 4k+i
        const float* row = sino + ((size_t)(4 * k + i) * NA + a) * NP + 8 * g;
        const float4 lo = *reinterpret_cast<const float4*>(row);
        const float4 hi = *reinterpret_cast<const float4*>(row + 4);
        float ex = __shfl_down(lo.x, 1, 64);      // s[8g+8] from lane g+1
        if (g == 63) ex = 0.0f;                   // s[512] OOB -> 0
        e[i][0] = pk(lo.x, lo.y);
        e[i][1] = pk(lo.y, lo.z);
        e[i][2] = pk(lo.z, lo.w);
        e[i][3] = pk(lo.w, hi.x);
        e[i][4] = pk(hi.x, hi.y);
        e[i][5] = pk(hi.y, hi.z);
        e[i][6] = pk(hi.z, hi.w);
        e[i][7] = pk(hi.w, ex);
    }

    uint4* dst = st + ((size_t)k * NA + a) * PS + 8 * g + 1;
#pragma unroll
    for (int j = 0; j < 8; ++j)
        dst[j] = make_uint4(e[0][j], e[1][j], e[2][j], e[3][j]);
}

// ---------------------------------------------------------------------------
// Proven round-10 backproject — UNCHANGED (113.5 us, 98% of LDS roofline).
// ---------------------------------------------------------------------------
__launch_bounds__(256)
__global__ void backproject(const uint4* __restrict__ st,
                            const float4* __restrict__ tab,
                            float* __restrict__ out) {
    __shared__ uint4 buf[2][ACH * 4 * NPT];     // 2 x 16 KB, [al][q][pt]
    __shared__ int pm_lds[NA];                  // 1.44 KB
    const int tid = threadIdx.y * 16 + threadIdx.x;
    const int x = blockIdx.x * 16 + threadIdx.x;
    const int y = blockIdx.y * 16 + threadIdx.y;
    const float xs = (float)x - 255.5f;
    const float ys = (float)y - 255.5f;
    const float xc = (float)(blockIdx.x * 16) + 7.5f - 255.5f;   // block center
    const float yc = (float)(blockIdx.y * 16) + 7.5f - 255.5f;

    for (int a = tid; a < NA; a += 256) {
        const float4 t = tab[a];
        float tc = fmaf(xc, t.x, fmaf(yc, t.y, t.z));
        pm_lds[a] = pmin_of(tc, t.w);
    }
    __syncthreads();

    float acc[NB];
#pragma unroll
    for (int b = 0; b < NB; ++b) acc[b] = 0.0f;

    const int qld = (tid >> 5) & 3;             // this thread's load plane
    const int ptl = tid & 31;                   // this thread's load point
    const int hl  = tid >> 7;                   // odd/even angle for loads

    auto issue = [&](int ch, int bsel) {
#pragma unroll
        for (int j = 0; j < 4; ++j) {
            const int a = ch * ACH + 2 * j + hl;
            const int pm = pm_lds[a];
            const uint4* gp = &st[(size_t)qld * (NA * PS) + (size_t)a * PS + pm + ptl];
            uint4* lp = &buf[bsel][tid + 256 * j];
            __builtin_amdgcn_global_load_lds(
                (__attribute__((address_space(1))) const void*)gp,
                (__attribute__((address_space(3))) void*)lp, 16, 0, 0);
        }
    };

    issue(0, 0);

#pragma unroll 1
    for (int ch = 0; ch < NCH; ++ch) {
        __syncthreads();                        // drains vmcnt: buf[ch&1] ready
        if (ch + 1 < NCH) issue(ch + 1, (ch + 1) & 1);

        const int a0 = ch * ACH;
        const uint4* b = buf[ch & 1];
#pragma unroll
        for (int al = 0; al < ACH; ++al) {
            const float4 t = tab[a0 + al];      // uniform -> s_load
            float fidx = fmaf(xs, t.x, fmaf(ys, t.y, t.z));
            fidx = fminf(fmaxf(fidx, -1.0f), 512.0f);
            const float fl = floorf(fidx);
            const float w = fidx - fl;
            const half2 wp = u2h(pk(1.0f - w, w));
            const int idx = ((int)fl + 1) - pm_lds[a0 + al];   // [0, 31]
            const uint4 d0 = b[al * 128 + 0 * 32 + idx];
            const uint4 d1 = b[al * 128 + 1 * 32 + idx];
            const uint4 d2 = b[al * 128 + 2 * 32 + idx];
            const uint4 d3 = b[al * 128 + 3 * 32 + idx];
            acc[0]  = dot2(wp, u2h(d0.x), acc[0]);
            acc[1]  = dot2(wp, u2h(d0.y), acc[1]);
            acc[2]  = dot2(wp, u2h(d0.z), acc[2]);
            acc[3]  = dot2(wp, u2h(d0.w), acc[3]);
            acc[4]  = dot2(wp, u2h(d1.x), acc[4]);
            acc[5]  = dot2(wp, u2h(d1.y), acc[5]);
            acc[6]  = dot2(wp, u2h(d1.z), acc[6]);
            acc[7]  = dot2(wp, u2h(d1.w), acc[7]);
            acc[8]  = dot2(wp, u2h(d2.x), acc[8]);
            acc[9]  = dot2(wp, u2h(d2.y), acc[9]);
            acc[10] = dot2(wp, u2h(d2.z), acc[10]);
            acc[11] = dot2(wp, u2h(d2.w), acc[11]);
            acc[12] = dot2(wp, u2h(d3.x), acc[12]);
            acc[13] = dot2(wp, u2h(d3.y), acc[13]);
            acc[14] = dot2(wp, u2h(d3.z), acc[14]);
            acc[15] = dot2(wp, u2h(d3.w), acc[15]);
        }
    }

    const size_t pix = (size_t)y * IMG + x;
#pragma unroll
    for (int b = 0; b < NB; ++b)
        out[(size_t)b * (IMG * IMG) + pix] = acc[b];
}

extern "C" void kernel_launch(void* const* d_in, const int* in_sizes, int n_in,
                              void* d_out, int out_size, void* d_ws, size_t ws_size,
                              hipStream_t stream) {
    const float* sino      = (const float*)d_in[0];
    const float* thetas    = (const float*)d_in[1];
    const float* positions = (const float*)d_in[2];
    float* out = (float*)d_out;

    float4* tab = (float4*)d_ws;                     // 360 * 16 B
    uint4*  st  = (uint4*)((char*)d_ws + 8192);      // 4 planes * 2.96 MB = 11.84 MB

    stage<<<dim3(NA + 1), dim3(256), 0, stream>>>(sino, thetas, positions, tab, st);
    backproject<<<dim3(IMG / 16, IMG / 16), dim3(16, 16), 0, stream>>>(st, tab, out);
}

// Round 6
// 174.707 us; speedup vs baseline: 1.2159x; 1.0023x over previous
//
#include <hip/hip_runtime.h>
#include <math.h>

#define NA 360
#define NP 512
#define NB 16
#define IMG 512
#define ACH 8                // angles per LDS chunk
#define NCH (NA / ACH)       // 45 chunks
#define NPT 32               // LDS points per angle (span <= 25 incl. margins)
#define PS 514               // p' in [0,513]; entry p' holds taps (s[p'-1], s[p'])
#define PS_GUARD (PS - NPT)  // 482

typedef unsigned int uint32;
typedef __fp16 half2 __attribute__((ext_vector_type(2)));   // builtin V2h type

static __device__ __forceinline__ half2 u2h(uint32 u) {
    union { uint32 u; half2 h; } v; v.u = u; return v.h;
}
static __device__ __forceinline__ uint32 pk(float a, float b) {
    union { half2 h; uint32 u; } v;
    v.h = __builtin_amdgcn_cvt_pkrtz(a, b);
    return v.u;
}

#if __has_builtin(__builtin_amdgcn_fdot2)
static __device__ __forceinline__ float dot2(half2 w, half2 v, float acc) {
    return __builtin_amdgcn_fdot2(w, v, acc, false);
}
#else
static __device__ __forceinline__ float dot2(half2 w, half2 v, float acc) {
    return fmaf((float)w.x, (float)v.x, fmaf((float)w.y, (float)v.y, acc));
}
#endif

// tab[a] = {c'=cos/dp, s'=sin/dp, off=-pos0/dp, (|c'|+|s'|)*7.5 (block half-span)}
static __device__ __forceinline__ void write_tab(const float* thetas,
                                                 const float* positions,
                                                 float4* tab, int a) {
    double th = (double)thetas[a];
    double p0 = (double)positions[0];
    double dp = (double)positions[1] - p0;
    double c = cos(th) / dp, s = sin(th) / dp;
    tab[a] = make_float4((float)c, (float)s, (float)(-p0 / dp),
                         (float)((fabs(c) + fabs(s)) * 7.5));
}

// Window start with 1-point lower margin against fp rounding (round-8 lesson).
static __device__ __forceinline__ int pmin_of(float tc, float tw) {
    float fmn = fminf(fmaxf(tc - tw, -1.0f), 512.0f);
    return min(max((int)floorf(fmn) - 1, 0), PS_GUARD);
}

// ---------------------------------------------------------------------------
// Round-18 stage: vectorized loads (round-17) + LDS-TRANSPOSED coalesced
// stores. Round-5 post-mortem: round-17's store loop was per-instruction
// scattered (store j: 64 lanes x 16 B at 128-B stride over 8 KB) -> ~8x store
// transactions on a 361-block grid with no TLP to hide them -> stage ~21 us,
// WORSE than the scalar round-0 stage (~14 us). Fix: transpose through LDS.
//   - produce: per batch row, 2 aligned dwordx4 + 9th tap via __shfl_down
//     (lane 63: s[512] OOB -> 0), 8 cvt_pkrtz packs.
//   - LDS write at slot (8g+j) ^ (g&7): per-instruction each 8-lane subgroup
//     covers all 32 banks -> conflict-free.
//   - __syncthreads; read at slot (g+64j) ^ ((g>>3)&7) (consecutive pattern,
//     conflict-free); store dst[g+64j]: fully-coalesced 1-KB instructions.
// Block = one angle (4 waves = 4 planes); block 360 does edges + tab.
// Backproject is the proven round-10 kernel VERBATIM (113.5 us = 98% of the
// ds_read_b128 issue roofline, conflicts 0). Grid-barrier fusion (r13/14:
// +80 us) and self-staging (r16: +58 us VALU) disproven — structure final.
// Budget: ~40 us fixed harness overhead + 113.7 backproject + ~5 stage.
// ---------------------------------------------------------------------------
__launch_bounds__(256)
__global__ void stage(const float* __restrict__ sino,
                      const float* __restrict__ thetas,
                      const float* __restrict__ positions,
                      float4* __restrict__ tab,
                      uint4* __restrict__ st) {
    const int tid = threadIdx.x;
    if (blockIdx.x == NA) {                       // edges + tab block
        for (int a = tid; a < NA; a += 256)
            write_tab(thetas, positions, tab, a);
        for (int n = tid; n < 4 * NA; n += 256) {
            const int k = n / NA;
            const int a = n - k * NA;
            const size_t base = ((size_t)k * NA + a) * PS;
            uint32 r[4];
#pragma unroll
            for (int i = 0; i < 4; ++i)
                r[i] = pk(0.0f, sino[((size_t)(4 * k + i) * NA + a) * NP]);
            st[base] = make_uint4(r[0], r[1], r[2], r[3]);
            st[base + (PS - 1)] = make_uint4(0u, 0u, 0u, 0u);
        }
        return;
    }

    __shared__ uint4 xb[4][512];                  // 32 KB transpose buffer

    const int a = blockIdx.x;                     // angle
    const int k = tid >> 6;                       // plane (== wave id)
    const int g = tid & 63;                       // group: entries 8g+1 .. 8g+8

    uint32 e[4][8];
#pragma unroll
    for (int i = 0; i < 4; ++i) {                 // batch 4k+i
        const float* row = sino + ((size_t)(4 * k + i) * NA + a) * NP + 8 * g;
        const float4 lo = *reinterpret_cast<const float4*>(row);
        const float4 hi = *reinterpret_cast<const float4*>(row + 4);
        float ex = __shfl_down(lo.x, 1, 64);      // s[8g+8] from lane g+1
        if (g == 63) ex = 0.0f;                   // s[512] OOB -> 0
        e[i][0] = pk(lo.x, lo.y);
        e[i][1] = pk(lo.y, lo.z);
        e[i][2] = pk(lo.z, lo.w);
        e[i][3] = pk(lo.w, hi.x);
        e[i][4] = pk(hi.x, hi.y);
        e[i][5] = pk(hi.y, hi.z);
        e[i][6] = pk(hi.z, hi.w);
        e[i][7] = pk(hi.w, ex);
    }

    // LDS write, swizzled (conflict-free: subgroup covers all 32 banks)
#pragma unroll
    for (int j = 0; j < 8; ++j)
        xb[k][(8 * g + j) ^ (g & 7)] = make_uint4(e[0][j], e[1][j], e[2][j], e[3][j]);
    __syncthreads();

    // Transposed read (conflict-free) + fully-coalesced global stores
    uint4* dst = st + ((size_t)k * NA + a) * PS + 1;
#pragma unroll
    for (int j = 0; j < 8; ++j)
        dst[g + 64 * j] = xb[k][(g + 64 * j) ^ ((g >> 3) & 7)];
}

// ---------------------------------------------------------------------------
// Proven round-10 backproject — UNCHANGED (113.5 us, 98% of LDS roofline).
// ---------------------------------------------------------------------------
__launch_bounds__(256)
__global__ void backproject(const uint4* __restrict__ st,
                            const float4* __restrict__ tab,
                            float* __restrict__ out) {
    __shared__ uint4 buf[2][ACH * 4 * NPT];     // 2 x 16 KB, [al][q][pt]
    __shared__ int pm_lds[NA];                  // 1.44 KB
    const int tid = threadIdx.y * 16 + threadIdx.x;
    const int x = blockIdx.x * 16 + threadIdx.x;
    const int y = blockIdx.y * 16 + threadIdx.y;
    const float xs = (float)x - 255.5f;
    const float ys = (float)y - 255.5f;
    const float xc = (float)(blockIdx.x * 16) + 7.5f - 255.5f;   // block center
    const float yc = (float)(blockIdx.y * 16) + 7.5f - 255.5f;

    for (int a = tid; a < NA; a += 256) {
        const float4 t = tab[a];
        float tc = fmaf(xc, t.x, fmaf(yc, t.y, t.z));
        pm_lds[a] = pmin_of(tc, t.w);
    }
    __syncthreads();

    float acc[NB];
#pragma unroll
    for (int b = 0; b < NB; ++b) acc[b] = 0.0f;

    const int qld = (tid >> 5) & 3;             // this thread's load plane
    const int ptl = tid & 31;                   // this thread's load point
    const int hl  = tid >> 7;                   // odd/even angle for loads

    auto issue = [&](int ch, int bsel) {
#pragma unroll
        for (int j = 0; j < 4; ++j) {
            const int a = ch * ACH + 2 * j + hl;
            const int pm = pm_lds[a];
            const uint4* gp = &st[(size_t)qld * (NA * PS) + (size_t)a * PS + pm + ptl];
            uint4* lp = &buf[bsel][tid + 256 * j];
            __builtin_amdgcn_global_load_lds(
                (__attribute__((address_space(1))) const void*)gp,
                (__attribute__((address_space(3))) void*)lp, 16, 0, 0);
        }
    };

    issue(0, 0);

#pragma unroll 1
    for (int ch = 0; ch < NCH; ++ch) {
        __syncthreads();                        // drains vmcnt: buf[ch&1] ready
        if (ch + 1 < NCH) issue(ch + 1, (ch + 1) & 1);

        const int a0 = ch * ACH;
        const uint4* b = buf[ch & 1];
#pragma unroll
        for (int al = 0; al < ACH; ++al) {
            const float4 t = tab[a0 + al];      // uniform -> s_load
            float fidx = fmaf(xs, t.x, fmaf(ys, t.y, t.z));
            fidx = fminf(fmaxf(fidx, -1.0f), 512.0f);
            const float fl = floorf(fidx);
            const float w = fidx - fl;
            const half2 wp = u2h(pk(1.0f - w, w));
            const int idx = ((int)fl + 1) - pm_lds[a0 + al];   // [0, 31]
            const uint4 d0 = b[al * 128 + 0 * 32 + idx];
            const uint4 d1 = b[al * 128 + 1 * 32 + idx];
            const uint4 d2 = b[al * 128 + 2 * 32 + idx];
            const uint4 d3 = b[al * 128 + 3 * 32 + idx];
            acc[0]  = dot2(wp, u2h(d0.x), acc[0]);
            acc[1]  = dot2(wp, u2h(d0.y), acc[1]);
            acc[2]  = dot2(wp, u2h(d0.z), acc[2]);
            acc[3]  = dot2(wp, u2h(d0.w), acc[3]);
            acc[4]  = dot2(wp, u2h(d1.x), acc[4]);
            acc[5]  = dot2(wp, u2h(d1.y), acc[5]);
            acc[6]  = dot2(wp, u2h(d1.z), acc[6]);
            acc[7]  = dot2(wp, u2h(d1.w), acc[7]);
            acc[8]  = dot2(wp, u2h(d2.x), acc[8]);
            acc[9]  = dot2(wp, u2h(d2.y), acc[9]);
            acc[10] = dot2(wp, u2h(d2.z), acc[10]);
            acc[11] = dot2(wp, u2h(d2.w), acc[11]);
            acc[12] = dot2(wp, u2h(d3.x), acc[12]);
            acc[13] = dot2(wp, u2h(d3.y), acc[13]);
            acc[14] = dot2(wp, u2h(d3.z), acc[14]);
            acc[15] = dot2(wp, u2h(d3.w), acc[15]);
        }
    }

    const size_t pix = (size_t)y * IMG + x;
#pragma unroll
    for (int b = 0; b < NB; ++b)
        out[(size_t)b * (IMG * IMG) + pix] = acc[b];
}

extern "C" void kernel_launch(void* const* d_in, const int* in_sizes, int n_in,
                              void* d_out, int out_size, void* d_ws, size_t ws_size,
                              hipStream_t stream) {
    const float* sino      = (const float*)d_in[0];
    const float* thetas    = (const float*)d_in[1];
    const float* positions = (const float*)d_in[2];
    float* out = (float*)d_out;

    float4* tab = (float4*)d_ws;                     // 360 * 16 B
    uint4*  st  = (uint4*)((char*)d_ws + 8192);      // 4 planes * 2.96 MB = 11.84 MB

    stage<<<dim3(NA + 1), dim3(256), 0, stream>>>(sino, thetas, positions, tab, st);
    backproject<<<dim3(IMG / 16, IMG / 16), dim3(16, 16), 0, stream>>>(st, tab, out);
}

// Round 7
// 165.701 us; speedup vs baseline: 1.2820x; 1.0543x over previous
//
#include <hip/hip_runtime.h>
#include <math.h>

#define NA 360
#define NP 512
#define NB 16
#define IMG 512
#define ACH 8                // angles per LDS chunk
#define NCH (NA / ACH)       // 45 chunks
#define NPT 32               // LDS points per angle (span <= 25 incl. margins)
#define PS 514               // p' in [0,513]; entry p' holds taps (s[p'-1], s[p'])
#define PS_GUARD (PS - NPT)  // 482
#define NTABB 6              // tab blocks (6 x 64 = 384 >= 360 angles)

typedef unsigned int uint32;
typedef __fp16 half2 __attribute__((ext_vector_type(2)));   // builtin V2h type

static __device__ __forceinline__ half2 u2h(uint32 u) {
    union { uint32 u; half2 h; } v; v.u = u; return v.h;
}
static __device__ __forceinline__ uint32 pk(float a, float b) {
    union { half2 h; uint32 u; } v;
    v.h = __builtin_amdgcn_cvt_pkrtz(a, b);
    return v.u;
}

#if __has_builtin(__builtin_amdgcn_fdot2)
static __device__ __forceinline__ float dot2(half2 w, half2 v, float acc) {
    return __builtin_amdgcn_fdot2(w, v, acc, false);
}
#else
static __device__ __forceinline__ float dot2(half2 w, half2 v, float acc) {
    return fmaf((float)w.x, (float)v.x, fmaf((float)w.y, (float)v.y, acc));
}
#endif

// tab[a] = {c'=cos/dp, s'=sin/dp, off=-pos0/dp, (|c'|+|s'|)*7.5 (block half-span)}
static __device__ __forceinline__ void write_tab(const float* thetas,
                                                 const float* positions,
                                                 float4* tab, int a) {
    double th = (double)thetas[a];
    double p0 = (double)positions[0];
    double dp = (double)positions[1] - p0;
    double c = cos(th) / dp, s = sin(th) / dp;
    tab[a] = make_float4((float)c, (float)s, (float)(-p0 / dp),
                         (float)((fabs(c) + fabs(s)) * 7.5));
}

// Window start with 1-point lower margin against fp rounding (round-8 lesson).
static __device__ __forceinline__ int pmin_of(float tc, float tw) {
    float fmn = fminf(fmaxf(tc - tw, -1.0f), 512.0f);
    return min(max((int)floorf(fmn) - 1, 0), PS_GUARD);
}

// ---------------------------------------------------------------------------
// Round-19 stage: PARALLELISM fix. Round-6 post-mortem: the LDS-transpose
// store fix was a NULL result (stage 21.5 -> 21.7 us) — stores were not the
// bottleneck. Discriminating evidence: round-0's scalar stage (2893 blocks)
// = ~14 us beats rounds-5/6 vectorized (361 blocks) = ~21.5 us despite ~4x
// more instructions -> the stage is LATENCY-bound; 1.4 blocks/CU gives no
// TLP to hide each thread's serial load->pack->LDS->store chain.
// This version: one WAVE per (plane, angle) row. 64-thread blocks, grid =
// 4*360 = 1440 main + 6 tab blocks ~= 5.6 blocks/CU (4x wave parallelism,
// 8 KB LDS/block -> up to 16 resident). Per-thread work identical to
// round-6 (2 dwordx4 + shfl 9th tap, 8 cvt_pkrtz, LDS-swizzled transpose,
// coalesced 1-KB store instructions). Edges fold into the owning block
// (thread 0 holds s[0] in lo.x -> pp=0 entry; pp=513 = zeros); fp64-trig
// tab spread over 6 dedicated blocks (no straggler).
// Backproject is the proven round-10 kernel VERBATIM (113.5 us = 98% of the
// ds_read_b128 issue roofline, conflicts 0). Grid-barrier fusion (r13/14:
// +80 us) and self-staging (r16: +45 us VALU) disproven — structure final.
// Budget: ~42 us fixed harness + 113.5 backproject + ~5 stage -> ~161.
// ---------------------------------------------------------------------------
__launch_bounds__(64)
__global__ void stage(const float* __restrict__ sino,
                      const float* __restrict__ thetas,
                      const float* __restrict__ positions,
                      float4* __restrict__ tab,
                      uint4* __restrict__ st) {
    const int bid = blockIdx.x;
    const int g   = threadIdx.x;                  // lane 0..63

    if (bid >= 4 * NA) {                          // tab blocks: trig only
        const int a = (bid - 4 * NA) * 64 + g;
        if (a < NA) write_tab(thetas, positions, tab, a);
        return;
    }

    __shared__ uint4 xb[512];                     // 8 KB transpose buffer

    const int k = bid / NA;                       // plane
    const int a = bid - k * NA;                   // angle

    uint32 e[4][8];
    uint32 r0[4];
#pragma unroll
    for (int i = 0; i < 4; ++i) {                 // batch 4k+i
        const float* row = sino + ((size_t)(4 * k + i) * NA + a) * NP + 8 * g;
        const float4 lo = *reinterpret_cast<const float4*>(row);
        const float4 hi = *reinterpret_cast<const float4*>(row + 4);
        float ex = __shfl_down(lo.x, 1, 64);      // s[8g+8] from lane g+1
        if (g == 63) ex = 0.0f;                   // s[512] OOB -> 0
        e[i][0] = pk(lo.x, lo.y);
        e[i][1] = pk(lo.y, lo.z);
        e[i][2] = pk(lo.z, lo.w);
        e[i][3] = pk(lo.w, hi.x);
        e[i][4] = pk(hi.x, hi.y);
        e[i][5] = pk(hi.y, hi.z);
        e[i][6] = pk(hi.z, hi.w);
        e[i][7] = pk(hi.w, ex);
        r0[i] = pk(0.0f, lo.x);                   // pp=0 entry: (0, s[0])
    }

    // LDS write, swizzled (per-instruction: 8-lane subgroups cover all banks)
#pragma unroll
    for (int j = 0; j < 8; ++j)
        xb[(8 * g + j) ^ (g & 7)] = make_uint4(e[0][j], e[1][j], e[2][j], e[3][j]);
    __syncthreads();

    // Transposed read (conflict-free) + fully-coalesced 1-KB global stores
    const size_t base = ((size_t)k * NA + a) * PS;
    uint4* dst = st + base + 1;
#pragma unroll
    for (int j = 0; j < 8; ++j)
        dst[g + 64 * j] = xb[(g + 64 * j) ^ ((g >> 3) & 7)];

    if (g == 0) st[base] = make_uint4(r0[0], r0[1], r0[2], r0[3]);
    if (g == 1) st[base + (PS - 1)] = make_uint4(0u, 0u, 0u, 0u);
}

// ---------------------------------------------------------------------------
// Proven round-10 backproject — UNCHANGED (113.5 us, 98% of LDS roofline).
// ---------------------------------------------------------------------------
__launch_bounds__(256)
__global__ void backproject(const uint4* __restrict__ st,
                            const float4* __restrict__ tab,
                            float* __restrict__ out) {
    __shared__ uint4 buf[2][ACH * 4 * NPT];     // 2 x 16 KB, [al][q][pt]
    __shared__ int pm_lds[NA];                  // 1.44 KB
    const int tid = threadIdx.y * 16 + threadIdx.x;
    const int x = blockIdx.x * 16 + threadIdx.x;
    const int y = blockIdx.y * 16 + threadIdx.y;
    const float xs = (float)x - 255.5f;
    const float ys = (float)y - 255.5f;
    const float xc = (float)(blockIdx.x * 16) + 7.5f - 255.5f;   // block center
    const float yc = (float)(blockIdx.y * 16) + 7.5f - 255.5f;

    for (int a = tid; a < NA; a += 256) {
        const float4 t = tab[a];
        float tc = fmaf(xc, t.x, fmaf(yc, t.y, t.z));
        pm_lds[a] = pmin_of(tc, t.w);
    }
    __syncthreads();

    float acc[NB];
#pragma unroll
    for (int b = 0; b < NB; ++b) acc[b] = 0.0f;

    const int qld = (tid >> 5) & 3;             // this thread's load plane
    const int ptl = tid & 31;                   // this thread's load point
    const int hl  = tid >> 7;                   // odd/even angle for loads

    auto issue = [&](int ch, int bsel) {
#pragma unroll
        for (int j = 0; j < 4; ++j) {
            const int a = ch * ACH + 2 * j + hl;
            const int pm = pm_lds[a];
            const uint4* gp = &st[(size_t)qld * (NA * PS) + (size_t)a * PS + pm + ptl];
            uint4* lp = &buf[bsel][tid + 256 * j];
            __builtin_amdgcn_global_load_lds(
                (__attribute__((address_space(1))) const void*)gp,
                (__attribute__((address_space(3))) void*)lp, 16, 0, 0);
        }
    };

    issue(0, 0);

#pragma unroll 1
    for (int ch = 0; ch < NCH; ++ch) {
        __syncthreads();                        // drains vmcnt: buf[ch&1] ready
        if (ch + 1 < NCH) issue(ch + 1, (ch + 1) & 1);

        const int a0 = ch * ACH;
        const uint4* b = buf[ch & 1];
#pragma unroll
        for (int al = 0; al < ACH; ++al) {
            const float4 t = tab[a0 + al];      // uniform -> s_load
            float fidx = fmaf(xs, t.x, fmaf(ys, t.y, t.z));
            fidx = fminf(fmaxf(fidx, -1.0f), 512.0f);
            const float fl = floorf(fidx);
            const float w = fidx - fl;
            const half2 wp = u2h(pk(1.0f - w, w));
            const int idx = ((int)fl + 1) - pm_lds[a0 + al];   // [0, 31]
            const uint4 d0 = b[al * 128 + 0 * 32 + idx];
            const uint4 d1 = b[al * 128 + 1 * 32 + idx];
            const uint4 d2 = b[al * 128 + 2 * 32 + idx];
            const uint4 d3 = b[al * 128 + 3 * 32 + idx];
            acc[0]  = dot2(wp, u2h(d0.x), acc[0]);
            acc[1]  = dot2(wp, u2h(d0.y), acc[1]);
            acc[2]  = dot2(wp, u2h(d0.z), acc[2]);
            acc[3]  = dot2(wp, u2h(d0.w), acc[3]);
            acc[4]  = dot2(wp, u2h(d1.x), acc[4]);
            acc[5]  = dot2(wp, u2h(d1.y), acc[5]);
            acc[6]  = dot2(wp, u2h(d1.z), acc[6]);
            acc[7]  = dot2(wp, u2h(d1.w), acc[7]);
            acc[8]  = dot2(wp, u2h(d2.x), acc[8]);
            acc[9]  = dot2(wp, u2h(d2.y), acc[9]);
            acc[10] = dot2(wp, u2h(d2.z), acc[10]);
            acc[11] = dot2(wp, u2h(d2.w), acc[11]);
            acc[12] = dot2(wp, u2h(d3.x), acc[12]);
            acc[13] = dot2(wp, u2h(d3.y), acc[13]);
            acc[14] = dot2(wp, u2h(d3.z), acc[14]);
            acc[15] = dot2(wp, u2h(d3.w), acc[15]);
        }
    }

    const size_t pix = (size_t)y * IMG + x;
#pragma unroll
    for (int b = 0; b < NB; ++b)
        out[(size_t)b * (IMG * IMG) + pix] = acc[b];
}

extern "C" void kernel_launch(void* const* d_in, const int* in_sizes, int n_in,
                              void* d_out, int out_size, void* d_ws, size_t ws_size,
                              hipStream_t stream) {
    const float* sino      = (const float*)d_in[0];
    const float* thetas    = (const float*)d_in[1];
    const float* positions = (const float*)d_in[2];
    float* out = (float*)d_out;

    float4* tab = (float4*)d_ws;                     // 360 * 16 B
    uint4*  st  = (uint4*)((char*)d_ws + 8192);      // 4 planes * 2.96 MB = 11.84 MB

    stage<<<dim3(4 * NA + NTABB), dim3(64), 0, stream>>>(sino, thetas, positions, tab, st);
    backproject<<<dim3(IMG / 16, IMG / 16), dim3(16, 16), 0, stream>>>(st, tab, out);
}